// Round 5
// baseline (801.843 us; speedup 1.0000x reference)
//
#include <hip/hip_runtime.h>

#define HW 128
#define NPIX 16384      // 128*128
#define CIN 256
#define NSC 147456      // NPIX*9
#define PRENMS 6000
#define POSTK 300
#define DW_CLIP_F 4.135166556742356f
#define MW 96           // u64 words per mask row
typedef unsigned long long ull;

// ---------------------------------------------------------------- zero scratch
__global__ void zero_kernel(unsigned* __restrict__ p, int n) {
    int i = blockIdx.x * 256 + threadIdx.x;
    if (i < n) p[i] = 0u;
}

// ---------------------------------------------------------------- weight transpose
// w: [co=256][k=2304] -> wt: [k=2304][co=256]
__global__ void wt_kernel(const float* __restrict__ w, float* __restrict__ wt) {
    int i = blockIdx.x * 256 + threadIdx.x;
    if (i < 2304 * 256) {
        int k = i >> 8, co = i & 255;
        wt[i] = w[co * 2304 + k];
    }
}

// ---------------------------------------------------------------- 3x3 conv + bias + relu
// feat: [256][128][128], wt: [2304][256], b: [256], out: [256][16384]
// block (16,16) = 16x16 spatial tile; z: 16 output channels -> 1024 blocks
// Double-buffered LDS: prefetch stage s+1 into regs before stage-s compute;
// one barrier per stage. Accumulation order identical to single-buffer version.
__global__ __launch_bounds__(256) void conv3x3_relu_kernel(
    const float* __restrict__ feat, const float* __restrict__ wt,
    const float* __restrict__ b, float* __restrict__ out)
{
    __shared__ float in_s[2][16 * 324];
    const int tx = threadIdx.x;
    const int ty = threadIdx.y;
    const int x0 = blockIdx.x * 16;
    const int y0 = blockIdx.y * 16;
    const int co0 = blockIdx.z * 16;
    const int tid = ty * 16 + tx;

    // staging geometry computed ONCE
    const int yy1 = tid / 18, xx1 = tid - yy1 * 18;
    const int t2 = tid + 256;
    const int yy2 = t2 / 18, xx2 = t2 - yy2 * 18;
    const int gy1 = y0 + yy1 - 1, gx1 = x0 + xx1 - 1;
    const int gy2 = y0 + yy2 - 1, gx2 = x0 + xx2 - 1;
    const bool p1 = ((unsigned)gy1 < 128u) && ((unsigned)gx1 < 128u);
    const bool p2 = (tid < 68) && ((unsigned)gy2 < 128u) && ((unsigned)gx2 < 128u);
    const int a1 = p1 ? (gy1 * 128 + gx1) : 0;
    const int a2 = p2 ? (gy2 * 128 + gx2) : 0;

    float acc[16];
#pragma unroll
    for (int i = 0; i < 16; ++i) acc[i] = 0.f;

    float r1[16], r2[16];
    // prefetch + write stage 0
#pragma unroll
    for (int ci = 0; ci < 16; ++ci) r1[ci] = feat[ci * NPIX + a1];
    if (tid < 68) {
#pragma unroll
        for (int ci = 0; ci < 16; ++ci) r2[ci] = feat[ci * NPIX + a2];
    }
#pragma unroll
    for (int ci = 0; ci < 16; ++ci) in_s[0][ci * 324 + tid] = p1 ? r1[ci] : 0.f;
    if (tid < 68) {
#pragma unroll
        for (int ci = 0; ci < 16; ++ci) in_s[0][ci * 324 + 256 + tid] = p2 ? r2[ci] : 0.f;
    }
    __syncthreads();

    for (int s = 0; s < 16; ++s) {
        const int cur = s & 1;
        // issue next stage's global loads BEFORE compute (latency hidden by FMAs)
        if (s < 15) {
            const float* fb = feat + (s + 1) * 16 * NPIX;
#pragma unroll
            for (int ci = 0; ci < 16; ++ci) r1[ci] = fb[ci * NPIX + a1];
            if (tid < 68) {
#pragma unroll
                for (int ci = 0; ci < 16; ++ci) r2[ci] = fb[ci * NPIX + a2];
            }
        }
        const float* ws0 = wt + s * 16 * 9 * 256 + co0;
#pragma unroll 4
        for (int ci = 0; ci < 16; ++ci) {
            const float* wrow = ws0 + ci * 9 * 256;
#pragma unroll
            for (int t = 0; t < 9; ++t) {
                const int ky = t / 3, kx = t - ky * 3;
                float v = in_s[cur][ci * 324 + (ty + ky) * 18 + (tx + kx)];
                const float* wp = wrow + t * 256;   // wave-uniform -> s_load_dwordx16
#pragma unroll
                for (int co = 0; co < 16; ++co)
                    acc[co] = fmaf(v, wp[co], acc[co]);
            }
        }
        if (s < 15) {
#pragma unroll
            for (int ci = 0; ci < 16; ++ci) in_s[cur ^ 1][ci * 324 + tid] = p1 ? r1[ci] : 0.f;
            if (tid < 68) {
#pragma unroll
                for (int ci = 0; ci < 16; ++ci) in_s[cur ^ 1][ci * 324 + 256 + tid] = p2 ? r2[ci] : 0.f;
            }
            __syncthreads();
        }
    }
#pragma unroll
    for (int co = 0; co < 16; ++co) {
        float r = acc[co] + b[co0 + co];
        out[(co0 + co) * NPIX + (y0 + ty) * 128 + (x0 + tx)] = fmaxf(r, 0.f);
    }
}

// ---------------------------------------------------------------- 1x1 heads: cls(9) + bbox(36)
// Weights staged in LDS once per block (broadcast ds_read_b128 in the loop)
// instead of 45 scalar s_loads per ci iteration. Accumulation order unchanged.
__global__ __launch_bounds__(64) void heads_kernel(
    const float* __restrict__ rf,
    const float* __restrict__ cls_w, const float* __restrict__ cls_b,
    const float* __restrict__ bbox_w, const float* __restrict__ bbox_b,
    float* __restrict__ scores, float* __restrict__ bb)
{
    __shared__ float wl[256][48];   // 49152 B; [ci][slot], slot 0-8 = cls, 9-44 = bbox
    const int tid = threadIdx.x;
    for (int e = tid; e < 256 * 45; e += 64) {
        int ci = e / 45, s = e - ci * 45;
        wl[ci][s] = (s < 9) ? cls_w[s * CIN + ci] : bbox_w[(s - 9) * CIN + ci];
    }
    __syncthreads();

    const int p = blockIdx.x * 64 + tid;
    float acc[45];
#pragma unroll
    for (int i = 0; i < 45; ++i) acc[i] = 0.f;

#pragma unroll 2
    for (int ci = 0; ci < CIN; ++ci) {
        float v = rf[ci * NPIX + p];
        const float4* wr = (const float4*)&wl[ci][0];
#pragma unroll
        for (int q = 0; q < 11; ++q) {
            float4 w4 = wr[q];                     // wave-uniform address -> LDS broadcast
            acc[q * 4 + 0] = fmaf(v, w4.x, acc[q * 4 + 0]);
            acc[q * 4 + 1] = fmaf(v, w4.y, acc[q * 4 + 1]);
            acc[q * 4 + 2] = fmaf(v, w4.z, acc[q * 4 + 2]);
            acc[q * 4 + 3] = fmaf(v, w4.w, acc[q * 4 + 3]);
        }
        acc[44] = fmaf(v, wl[ci][44], acc[44]);
    }
#pragma unroll
    for (int a = 0; a < 9; ++a) {
        float s = acc[a] + cls_b[a];
        scores[p * 9 + a] = 1.0f / (1.0f + expf(-s));
    }
#pragma unroll
    for (int c = 0; c < 36; ++c) {
        bb[c * NPIX + p] = acc[9 + c] + bbox_b[c];
    }
}

// ---------------------------------------------------------------- top-k select: histograms
__global__ __launch_bounds__(1024) void hist1_kernel(const float* __restrict__ scores,
                                                     unsigned* __restrict__ hist1) {
    __shared__ unsigned h[16384];
    const int tid = threadIdx.x;
    for (int i = tid; i < 16384; i += 1024) h[i] = 0u;
    __syncthreads();
    for (int i = blockIdx.x * 1024 + tid; i < NSC; i += gridDim.x * 1024) {
        unsigned bits = __float_as_uint(scores[i]);
        atomicAdd(&h[bits >> 16], 1u);
    }
    __syncthreads();
    for (int i = tid; i < 16384; i += 1024) {
        unsigned c = h[i];
        if (c) atomicAdd(&hist1[i], c);
    }
}

// parallel suffix-scan (Hillis-Steele) replaces the serial thread-0 loop
__global__ __launch_bounds__(1024) void scan1_kernel(const unsigned* __restrict__ hist,
                                                     unsigned* __restrict__ meta) {
    __shared__ unsigned ssum[1024];
    const int t = threadIdx.x;
    unsigned local[16];
    unsigned s = 0;
#pragma unroll
    for (int i = 0; i < 16; ++i) { local[i] = hist[t * 16 + i]; s += local[i]; }
    ssum[t] = s;
    __syncthreads();
    for (int off = 1; off < 1024; off <<= 1) {
        unsigned v = ssum[t] + ((t + off < 1024) ? ssum[t + off] : 0u);
        __syncthreads();
        ssum[t] = v;
        __syncthreads();
    }
    unsigned run = ssum[t] - s;   // count in bins handled by threads > t
#pragma unroll
    for (int i = 15; i >= 0; --i) {
        unsigned nb = run + local[i];
        if (nb >= (unsigned)PRENMS && run < (unsigned)PRENMS) {
            meta[1] = (unsigned)(t * 16 + i);
            meta[2] = run;
        }
        run = nb;
    }
}

__global__ void hist2_kernel(const float* __restrict__ scores, const unsigned* __restrict__ meta,
                             unsigned* __restrict__ hist2) {
    int i = blockIdx.x * 256 + threadIdx.x;
    if (i < NSC) {
        unsigned bits = __float_as_uint(scores[i]);
        if ((bits >> 16) == meta[1]) atomicAdd(&hist2[bits & 0xFFFFu], 1u);
    }
}

__global__ __launch_bounds__(1024) void scan2_kernel(const unsigned* __restrict__ hist2,
                                                     unsigned* __restrict__ meta) {
    __shared__ unsigned ssum[1024];
    const int t = threadIdx.x;
    const unsigned need = (unsigned)PRENMS - meta[2];
    unsigned s = 0;
    for (int i = 0; i < 64; ++i) s += hist2[t * 64 + i];
    ssum[t] = s;
    __syncthreads();
    for (int off = 1; off < 1024; off <<= 1) {
        unsigned v = ssum[t] + ((t + off < 1024) ? ssum[t + off] : 0u);
        __syncthreads();
        ssum[t] = v;
        __syncthreads();
    }
    unsigned run = ssum[t] - s;
    for (int i = 63; i >= 0; --i) {
        unsigned h = hist2[t * 64 + i];
        unsigned nb = run + h;
        if (nb >= need && run < need) {
            meta[3] = (meta[1] << 16) | (unsigned)(t * 64 + i);
        }
        run = nb;
    }
}

// wave-aggregated compaction: 1 atomic per wave
__global__ void compact_kernel(const float* __restrict__ scores, unsigned* __restrict__ meta,
                               ull* __restrict__ cand) {
    int i = blockIdx.x * 256 + threadIdx.x;
    unsigned bits = (i < NSC) ? __float_as_uint(scores[i]) : 0u;
    bool pred = (i < NSC) && (bits >= meta[3]);
    ull bal = __ballot(pred);
    int lane = threadIdx.x & 63;
    unsigned cnt = (unsigned)__popcll(bal);
    unsigned base = 0;
    if (lane == 0 && cnt) base = atomicAdd(&meta[0], cnt);
    base = __shfl(base, 0);
    if (pred) {
        unsigned off = (unsigned)__popcll(bal & ((1ull << lane) - 1ull));
        unsigned pos = base + off;
        if (pos < 8192u)
            cand[pos] = ((ull)bits << 32) | (unsigned)(~i);
    }
}

// ---------------------------------------------------------------- parallel sort: 4 local sorts + rank-merge
__global__ __launch_bounds__(1024) void sortA_kernel(const ull* __restrict__ cand,
                                                     const unsigned* __restrict__ meta,
                                                     ull* __restrict__ sorted) {
    __shared__ ull keys[2048];
    const int tid = threadIdx.x;
    const int base = blockIdx.x * 2048;
    const int n = min((int)meta[0], 8192);
    for (int i = tid; i < 2048; i += 1024) {
        int g = base + i;
        keys[i] = (g < n) ? cand[g] : (ull)(8191 - g);
    }
    __syncthreads();
    for (int k = 2; k <= 2048; k <<= 1) {
        for (int j = k >> 1; j >= 1; j >>= 1) {
            int s = tid;
            int i = ((s & ~(j - 1)) << 1) | (s & (j - 1));
            int p = i | j;
            ull a = keys[i], c = keys[p];
            bool desc = ((i & k) == 0);
            bool sw = desc ? (a < c) : (a > c);
            if (sw) { keys[i] = c; keys[p] = a; }
            __syncthreads();
        }
    }
    for (int i = tid; i < 2048; i += 1024) sorted[base + i] = keys[i];
}

__global__ __launch_bounds__(256) void merge_kernel(const ull* __restrict__ sorted,
                                                    ull* __restrict__ fin) {
    const int g = blockIdx.x * 256 + threadIdx.x;   // 32 blocks -> 8192
    ull x = sorted[g];
    const int c = g >> 11;
    int rank = g & 2047;
#pragma unroll
    for (int cc = 0; cc < 4; ++cc) {
        if (cc == c) continue;
        const ull* arr = sorted + cc * 2048;
        int lo = 0, hi = 2048;
        while (lo < hi) { int mid = (lo + hi) >> 1; if (arr[mid] > x) lo = mid + 1; else hi = mid; }
        rank += lo;
    }
    fin[rank] = x;
}

// ---------------------------------------------------------------- decode top-6000 (parallel)
__global__ __launch_bounds__(64) void decode_kernel(
    const ull* __restrict__ fin, const float* __restrict__ bb,
    float* __restrict__ selbox, float* __restrict__ selsc,
    ull* __restrict__ validbits)
{
    const int r = blockIdx.x * 64 + threadIdx.x;
    int valid = 0;
    if (r < PRENMS) {
        ull key = fin[r];
        unsigned sbits = (unsigned)(key >> 32);
        unsigned idx = ~(unsigned)(key & 0xFFFFFFFFull);
        float score = __uint_as_float(sbits);
        int p = (int)(idx / 9u);
        int a = (int)(idx - (unsigned)p * 9u);
        int y = p >> 7, x = p & 127;
        float d0 = bb[(a * 4 + 0) * NPIX + p];
        float d1 = bb[(a * 4 + 1) * NPIX + p];
        float d2 = bb[(a * 4 + 2) * NPIX + p];
        float d3 = bb[(a * 4 + 3) * NPIX + p];
        int ar_i = a / 3, sc_i = a - ar_i * 3;
        float arv = (ar_i == 0) ? 0.5f : ((ar_i == 1) ? 1.0f : 2.0f);
        float scv = (sc_i == 0) ? 128.f : ((sc_i == 1) ? 256.f : 512.f);
        float hr = sqrtf(arv);
        float wr = 1.0f / hr;
        float hs = hr * scv;
        float wsv = wr * scv;
        float bx1 = rintf(-wsv * 0.5f), by1 = rintf(-hs * 0.5f);
        float bx2 = rintf(wsv * 0.5f),  by2 = rintf(hs * 0.5f);
        float ax1 = x * 8.f + bx1, ay1 = y * 8.f + by1;
        float ax2 = x * 8.f + bx2, ay2 = y * 8.f + by2;
        float wa = ax2 - ax1, ha = ay2 - ay1;
        float cx = ax1 + 0.5f * wa, cy = ay1 + 0.5f * ha;
        float dw = fminf(d2, DW_CLIP_F), dh = fminf(d3, DW_CLIP_F);
        float px = d0 * wa + cx, py = d1 * ha + cy;
        float pw = expf(dw) * wa, ph = expf(dh) * ha;
        float x1 = px - 0.5f * pw, y1 = py - 0.5f * ph;
        float x2 = px + 0.5f * pw, y2 = py + 0.5f * ph;
        x1 = fminf(fmaxf(x1, 0.f), 1024.f);
        y1 = fminf(fmaxf(y1, 0.f), 1024.f);
        x2 = fminf(fmaxf(x2, 0.f), 1024.f);
        y2 = fminf(fmaxf(y2, 0.f), 1024.f);
        float bw = x2 - x1, bh = y2 - y1;
        valid = (bw >= 16.f) && (bh >= 16.f);
        selbox[r * 4 + 0] = x1; selbox[r * 4 + 1] = y1;
        selbox[r * 4 + 2] = x2; selbox[r * 4 + 3] = y2;
        selsc[r] = score;
    }
    ull bal = __ballot(valid);
    if (threadIdx.x == 0) validbits[blockIdx.x] = bal;
}

// ---------------------------------------------------------------- IOU suppression mask build
__global__ __launch_bounds__(256) void maskbuild_kernel(
    const float* __restrict__ selbox, ull* __restrict__ mask)
{
    __shared__ float jb0[64], jb1[64], jb2[64], jb3[64];
    const int jw = blockIdx.y;
    const int tid = threadIdx.x;
    const int i = blockIdx.x * 256 + tid;
    // early-out: whole j-chunk strictly below this block's i-range -> all-zero words
    if (jw * 64 + 63 < blockIdx.x * 256) {
        if (i < PRENMS) mask[(size_t)i * MW + jw] = 0ull;
        return;
    }
    if (tid < 64) {
        int j = jw * 64 + tid;
        float x1 = 0.f, y1 = 0.f, x2 = 0.f, y2 = 0.f;
        if (j < PRENMS) {
            x1 = selbox[j * 4 + 0]; y1 = selbox[j * 4 + 1];
            x2 = selbox[j * 4 + 2]; y2 = selbox[j * 4 + 3];
        }
        jb0[tid] = x1; jb1[tid] = y1; jb2[tid] = x2; jb3[tid] = y2;
    }
    __syncthreads();
    if (i >= PRENMS) return;
    const float ix1 = selbox[i * 4 + 0], iy1 = selbox[i * 4 + 1];
    const float ix2 = selbox[i * 4 + 2], iy2 = selbox[i * 4 + 3];
    const float iarea = (ix2 - ix1) * (iy2 - iy1);
    ull word = 0ull;
    for (int b = 0; b < 64; ++b) {
        int j = jw * 64 + b;
        float xx1 = fmaxf(ix1, jb0[b]);
        float yy1 = fmaxf(iy1, jb1[b]);
        float xx2 = fminf(ix2, jb2[b]);
        float yy2 = fminf(iy2, jb3[b]);
        float iw = fmaxf(xx2 - xx1, 0.f);
        float ih = fmaxf(yy2 - yy1, 0.f);
        float inter = iw * ih;
        float jarea = (jb2[b] - jb0[b]) * (jb3[b] - jb1[b]);
        float iou = inter / (iarea + jarea - inter);
        if (j > i && iou > 0.7f) word |= (1ull << b);
    }
    mask[(size_t)i * MW + jw] = word;
}

// ---------------------------------------------------------------- chunked single-wave greedy NMS
__global__ __launch_bounds__(64) void nms_scan_kernel(
    const ull* __restrict__ validbits,
    const ull* __restrict__ mask,
    const float* __restrict__ selbox, const float* __restrict__ selsc,
    float* __restrict__ out)
{
    __shared__ int kept[POSTK];
    const int l = threadIdx.x;
    ull supp0 = ~validbits[l];
    ull supp1 = (l < 30) ? ~validbits[64 + l] : ~0ull;
    int nk = 0;
    ull ownrow_next = mask[(size_t)l * MW + 0];
    for (int wi = 0; wi < 94 && nk < POSTK; ++wi) {
        ull ownrow = ownrow_next;
        if (wi < 93) ownrow_next = mask[(size_t)((wi + 1) * 64 + l) * MW + (wi + 1)];
        ull wsup = (wi < 64) ? __shfl(supp0, wi) : __shfl(supp1, wi - 64);
        ull active = ~wsup;
        if (!active) continue;
        ull keptbits = 0ull;
        while (active && nk < POSTK) {
            int b = __builtin_ctzll(active);
            keptbits |= (1ull << b);
            if (l == 0) kept[nk] = wi * 64 + b;
            nk++;
            ull rowb = __shfl(ownrow, b);
            ull gt = (b == 63) ? 0ull : (~0ull << (b + 1));
            active &= gt & ~rowb;
        }
        while (keptbits) {
            int b0 = __builtin_ctzll(keptbits); keptbits &= keptbits - 1;
            int b1 = -1, b2 = -1, b3 = -1;
            if (keptbits) { b1 = __builtin_ctzll(keptbits); keptbits &= keptbits - 1; }
            if (keptbits) { b2 = __builtin_ctzll(keptbits); keptbits &= keptbits - 1; }
            if (keptbits) { b3 = __builtin_ctzll(keptbits); keptbits &= keptbits - 1; }
            const ull* r0 = mask + (size_t)(wi * 64 + b0) * MW;
            ull t0a = r0[l], t0b = (l < 30) ? r0[64 + l] : 0ull;
            ull t1a = 0, t1b = 0, t2a = 0, t2b = 0, t3a = 0, t3b = 0;
            if (b1 >= 0) { const ull* r1 = mask + (size_t)(wi * 64 + b1) * MW; t1a = r1[l]; t1b = (l < 30) ? r1[64 + l] : 0ull; }
            if (b2 >= 0) { const ull* r2 = mask + (size_t)(wi * 64 + b2) * MW; t2a = r2[l]; t2b = (l < 30) ? r2[64 + l] : 0ull; }
            if (b3 >= 0) { const ull* r3 = mask + (size_t)(wi * 64 + b3) * MW; t3a = r3[l]; t3b = (l < 30) ? r3[64 + l] : 0ull; }
            supp0 |= t0a | t1a | t2a | t3a;
            supp1 |= t0b | t1b | t2b | t3b;
        }
    }
    __syncthreads();
    for (int r = l; r < POSTK; r += 64) {
        if (r < nk) {
            int i = kept[r];
            out[r * 5 + 0] = selbox[i * 4 + 0];
            out[r * 5 + 1] = selbox[i * 4 + 1];
            out[r * 5 + 2] = selbox[i * 4 + 2];
            out[r * 5 + 3] = selbox[i * 4 + 3];
            out[r * 5 + 4] = selsc[i];
        } else {
            out[r * 5 + 0] = 0.f; out[r * 5 + 1] = 0.f;
            out[r * 5 + 2] = 0.f; out[r * 5 + 3] = 0.f;
            out[r * 5 + 4] = 0.f;
        }
    }
}

// ---------------------------------------------------------------- launch
extern "C" void kernel_launch(void* const* d_in, const int* in_sizes, int n_in,
                              void* d_out, int out_size, void* d_ws, size_t ws_size,
                              hipStream_t stream) {
    const float* feat    = (const float*)d_in[1];
    const float* conv_w  = (const float*)d_in[2];
    const float* conv_b  = (const float*)d_in[3];
    const float* cls_w   = (const float*)d_in[4];
    const float* cls_b   = (const float*)d_in[5];
    const float* bbox_w  = (const float*)d_in[6];
    const float* bbox_b  = (const float*)d_in[7];
    float* out = (float*)d_out;

    char* ws = (char*)d_ws;
    float*    rpn_feat  = (float*)(ws + 0);                 // 16,777,216
    float*    wt        = (float*)(ws + 16777216);          //  2,359,296
    float*    bb        = (float*)(ws + 19136512);          //  2,359,296
    float*    scores    = (float*)(ws + 21495808);          //    589,824
    unsigned* hist1     = (unsigned*)(ws + 22085632);       //     65,536
    unsigned* hist2     = (unsigned*)(ws + 22151168);       //    262,144
    unsigned* meta      = (unsigned*)(ws + 22413312);       //        256
    ull*      cand      = (ull*)(ws + 22413568);            //     65,536
    ull*      sorted    = (ull*)(ws + 22479104);            //     65,536
    ull*      fin       = (ull*)(ws + 22544640);            //     65,536
    float*    selbox    = (float*)(ws + 22610176);          //     96,256
    float*    selsc     = (float*)(ws + 22706432);          //     24,064
    ull*      validbits = (ull*)(ws + 22730496);            //        768
    ull*      mask      = (ull*)(ws + 22731264);            //  4,608,000

    {
        int nz = 16384 + 65536 + 64;  // hist1 + hist2 + meta contiguous
        zero_kernel<<<(nz + 255) / 256, 256, 0, stream>>>(hist1, nz);
    }
    wt_kernel<<<(2304 * 256 + 255) / 256, 256, 0, stream>>>(conv_w, wt);
    conv3x3_relu_kernel<<<dim3(8, 8, 16), dim3(16, 16), 0, stream>>>(feat, wt, conv_b, rpn_feat);
    heads_kernel<<<256, 64, 0, stream>>>(rpn_feat, cls_w, cls_b, bbox_w, bbox_b, scores, bb);
    hist1_kernel<<<64, 1024, 0, stream>>>(scores, hist1);
    scan1_kernel<<<1, 1024, 0, stream>>>(hist1, meta);
    hist2_kernel<<<(NSC + 255) / 256, 256, 0, stream>>>(scores, meta, hist2);
    scan2_kernel<<<1, 1024, 0, stream>>>(hist2, meta);
    compact_kernel<<<(NSC + 255) / 256, 256, 0, stream>>>(scores, meta, cand);
    sortA_kernel<<<4, 1024, 0, stream>>>(cand, meta, sorted);
    merge_kernel<<<32, 256, 0, stream>>>(sorted, fin);
    decode_kernel<<<94, 64, 0, stream>>>(fin, bb, selbox, selsc, validbits);
    maskbuild_kernel<<<dim3(24, 94), 256, 0, stream>>>(selbox, mask);
    nms_scan_kernel<<<1, 64, 0, stream>>>(validbits, mask, selbox, selsc, out);
}

// Round 6
// 584.628 us; speedup vs baseline: 1.3715x; 1.3715x over previous
//
#include <hip/hip_runtime.h>

#define HW 128
#define NPIX 16384      // 128*128
#define CIN 256
#define NSC 147456      // NPIX*9
#define PRENMS 6000
#define POSTK 300
#define DW_CLIP_F 4.135166556742356f
#define MW 96           // u64 words per mask row
typedef unsigned long long ull;

// ---------------------------------------------------------------- zero scratch
__global__ void zero_kernel(unsigned* __restrict__ p, int n) {
    int i = blockIdx.x * 256 + threadIdx.x;
    if (i < n) p[i] = 0u;
}

// ---------------------------------------------------------------- weight transpose
// w: [co=256][k=2304] -> wt: [k=2304][co=256]
__global__ void wt_kernel(const float* __restrict__ w, float* __restrict__ wt) {
    int i = blockIdx.x * 256 + threadIdx.x;
    if (i < 2304 * 256) {
        int k = i >> 8, co = i & 255;
        wt[i] = w[co * 2304 + k];
    }
}

// ---------------------------------------------------------------- 3x3 conv, K-split halves
// feat: [256][128][128], wt: [2304][256], part: [2][256][16384]
// blockIdx.z in [0,32): h = z>>4 selects ci-half, (z&15) selects 16-co group.
// 2048 blocks -> 8 blocks/CU -> 32 waves/CU (grid-cap removed vs 1024-block version).
// Single-buffer LDS (R3 structure: 36 VGPR, 20.5 KB LDS -- dbuf regressed, see R4).
__global__ __launch_bounds__(256) void conv3x3_half_kernel(
    const float* __restrict__ feat, const float* __restrict__ wt,
    float* __restrict__ part)
{
    __shared__ float in_s[16 * 324];
    const int tx = threadIdx.x;
    const int ty = threadIdx.y;
    const int x0 = blockIdx.x * 16;
    const int y0 = blockIdx.y * 16;
    const int h  = blockIdx.z >> 4;
    const int co0 = (blockIdx.z & 15) << 4;
    const int tid = ty * 16 + tx;

    // staging geometry computed ONCE
    const int yy1 = tid / 18, xx1 = tid - yy1 * 18;
    const int t2 = tid + 256;
    const int yy2 = t2 / 18, xx2 = t2 - yy2 * 18;
    const int gy1 = y0 + yy1 - 1, gx1 = x0 + xx1 - 1;
    const int gy2 = y0 + yy2 - 1, gx2 = x0 + xx2 - 1;
    const bool p1 = ((unsigned)gy1 < 128u) && ((unsigned)gx1 < 128u);
    const bool p2 = (tid < 68) && ((unsigned)gy2 < 128u) && ((unsigned)gx2 < 128u);
    const int a1 = p1 ? (gy1 * 128 + gx1) : 0;
    const int a2 = p2 ? (gy2 * 128 + gx2) : 0;

    float acc[16];
#pragma unroll
    for (int i = 0; i < 16; ++i) acc[i] = 0.f;

    const float* fh = feat + h * 128 * NPIX;
    const float* wh = wt + h * 128 * 9 * 256;

    for (int s = 0; s < 8; ++s) {
        __syncthreads();
        const float* fbase = fh + s * 16 * NPIX;
#pragma unroll
        for (int ci = 0; ci < 16; ++ci) {
            float t = fbase[ci * NPIX + a1];
            in_s[ci * 324 + tid] = p1 ? t : 0.f;
        }
        if (tid < 68) {
#pragma unroll
            for (int ci = 0; ci < 16; ++ci) {
                float t = fbase[ci * NPIX + a2];
                in_s[ci * 324 + 256 + tid] = p2 ? t : 0.f;
            }
        }
        __syncthreads();
        const float* ws0 = wh + s * 16 * 9 * 256 + co0;
#pragma unroll 4
        for (int ci = 0; ci < 16; ++ci) {
            const float* wrow = ws0 + ci * 9 * 256;
#pragma unroll
            for (int t = 0; t < 9; ++t) {
                const int ky = t / 3, kx = t - ky * 3;
                float v = in_s[ci * 324 + (ty + ky) * 18 + (tx + kx)];
                const float* wp = wrow + t * 256;   // wave-uniform -> s_load_dwordx16
#pragma unroll
                for (int co = 0; co < 16; ++co)
                    acc[co] = fmaf(v, wp[co], acc[co]);
            }
        }
    }
    float* po = part + h * (CIN * NPIX) + co0 * NPIX + (y0 + ty) * 128 + (x0 + tx);
#pragma unroll
    for (int co = 0; co < 16; ++co)
        po[co * NPIX] = acc[co];
}

// combine halves + bias + relu, float4 vectorized, in-place on part0 region
__global__ __launch_bounds__(256) void combine_kernel(
    float* __restrict__ part, const float* __restrict__ b)
{
    const int i = blockIdx.x * 256 + threadIdx.x;   // 1,048,576 float4s
    float4 a = ((const float4*)part)[i];
    float4 c = ((const float4*)(part + CIN * NPIX))[i];
    float bias = b[i >> 12];                         // 4096 float4s per channel
    float4 r;
    r.x = fmaxf(a.x + c.x + bias, 0.f);
    r.y = fmaxf(a.y + c.y + bias, 0.f);
    r.z = fmaxf(a.z + c.z + bias, 0.f);
    r.w = fmaxf(a.w + c.w + bias, 0.f);
    ((float4*)part)[i] = r;
}

// ---------------------------------------------------------------- 1x1 heads: cls(9) + bbox(36)
__global__ __launch_bounds__(64) void heads_kernel(
    const float* __restrict__ rf,
    const float* __restrict__ cls_w, const float* __restrict__ cls_b,
    const float* __restrict__ bbox_w, const float* __restrict__ bbox_b,
    float* __restrict__ scores, float* __restrict__ bb)
{
    __shared__ float wl[256][48];   // [ci][slot], 0-8 = cls, 9-44 = bbox
    const int tid = threadIdx.x;
    for (int e = tid; e < 256 * 45; e += 64) {
        int ci = e / 45, s = e - ci * 45;
        wl[ci][s] = (s < 9) ? cls_w[s * CIN + ci] : bbox_w[(s - 9) * CIN + ci];
    }
    __syncthreads();

    const int p = blockIdx.x * 64 + tid;
    float acc[45];
#pragma unroll
    for (int i = 0; i < 45; ++i) acc[i] = 0.f;

#pragma unroll 2
    for (int ci = 0; ci < CIN; ++ci) {
        float v = rf[ci * NPIX + p];
        const float4* wr = (const float4*)&wl[ci][0];
#pragma unroll
        for (int q = 0; q < 11; ++q) {
            float4 w4 = wr[q];
            acc[q * 4 + 0] = fmaf(v, w4.x, acc[q * 4 + 0]);
            acc[q * 4 + 1] = fmaf(v, w4.y, acc[q * 4 + 1]);
            acc[q * 4 + 2] = fmaf(v, w4.z, acc[q * 4 + 2]);
            acc[q * 4 + 3] = fmaf(v, w4.w, acc[q * 4 + 3]);
        }
        acc[44] = fmaf(v, wl[ci][44], acc[44]);
    }
#pragma unroll
    for (int a = 0; a < 9; ++a) {
        float s = acc[a] + cls_b[a];
        scores[p * 9 + a] = 1.0f / (1.0f + expf(-s));
    }
#pragma unroll
    for (int c = 0; c < 36; ++c) {
        bb[c * NPIX + p] = acc[9 + c] + bbox_b[c];
    }
}

// ---------------------------------------------------------------- top-k select: histograms
__global__ __launch_bounds__(1024) void hist1_kernel(const float* __restrict__ scores,
                                                     unsigned* __restrict__ hist1) {
    __shared__ unsigned h[16384];
    const int tid = threadIdx.x;
    for (int i = tid; i < 16384; i += 1024) h[i] = 0u;
    __syncthreads();
    for (int i = blockIdx.x * 1024 + tid; i < NSC; i += gridDim.x * 1024) {
        unsigned bits = __float_as_uint(scores[i]);
        atomicAdd(&h[bits >> 16], 1u);
    }
    __syncthreads();
    for (int i = tid; i < 16384; i += 1024) {
        unsigned c = h[i];
        if (c) atomicAdd(&hist1[i], c);
    }
}

__global__ __launch_bounds__(1024) void scan1_kernel(const unsigned* __restrict__ hist,
                                                     unsigned* __restrict__ meta) {
    __shared__ unsigned ssum[1024];
    const int t = threadIdx.x;
    unsigned local[16];
    unsigned s = 0;
#pragma unroll
    for (int i = 0; i < 16; ++i) { local[i] = hist[t * 16 + i]; s += local[i]; }
    ssum[t] = s;
    __syncthreads();
    for (int off = 1; off < 1024; off <<= 1) {
        unsigned v = ssum[t] + ((t + off < 1024) ? ssum[t + off] : 0u);
        __syncthreads();
        ssum[t] = v;
        __syncthreads();
    }
    unsigned run = ssum[t] - s;
#pragma unroll
    for (int i = 15; i >= 0; --i) {
        unsigned nb = run + local[i];
        if (nb >= (unsigned)PRENMS && run < (unsigned)PRENMS) {
            meta[1] = (unsigned)(t * 16 + i);
            meta[2] = run;
        }
        run = nb;
    }
}

__global__ void hist2_kernel(const float* __restrict__ scores, const unsigned* __restrict__ meta,
                             unsigned* __restrict__ hist2) {
    int i = blockIdx.x * 256 + threadIdx.x;
    if (i < NSC) {
        unsigned bits = __float_as_uint(scores[i]);
        if ((bits >> 16) == meta[1]) atomicAdd(&hist2[bits & 0xFFFFu], 1u);
    }
}

__global__ __launch_bounds__(1024) void scan2_kernel(const unsigned* __restrict__ hist2,
                                                     unsigned* __restrict__ meta) {
    __shared__ unsigned ssum[1024];
    const int t = threadIdx.x;
    const unsigned need = (unsigned)PRENMS - meta[2];
    unsigned s = 0;
    for (int i = 0; i < 64; ++i) s += hist2[t * 64 + i];
    ssum[t] = s;
    __syncthreads();
    for (int off = 1; off < 1024; off <<= 1) {
        unsigned v = ssum[t] + ((t + off < 1024) ? ssum[t + off] : 0u);
        __syncthreads();
        ssum[t] = v;
        __syncthreads();
    }
    unsigned run = ssum[t] - s;
    for (int i = 63; i >= 0; --i) {
        unsigned h = hist2[t * 64 + i];
        unsigned nb = run + h;
        if (nb >= need && run < need) {
            meta[3] = (meta[1] << 16) | (unsigned)(t * 64 + i);
        }
        run = nb;
    }
}

// wave-aggregated compaction: 1 atomic per wave
__global__ void compact_kernel(const float* __restrict__ scores, unsigned* __restrict__ meta,
                               ull* __restrict__ cand) {
    int i = blockIdx.x * 256 + threadIdx.x;
    unsigned bits = (i < NSC) ? __float_as_uint(scores[i]) : 0u;
    bool pred = (i < NSC) && (bits >= meta[3]);
    ull bal = __ballot(pred);
    int lane = threadIdx.x & 63;
    unsigned cnt = (unsigned)__popcll(bal);
    unsigned base = 0;
    if (lane == 0 && cnt) base = atomicAdd(&meta[0], cnt);
    base = __shfl(base, 0);
    if (pred) {
        unsigned off = (unsigned)__popcll(bal & ((1ull << lane) - 1ull));
        unsigned pos = base + off;
        if (pos < 8192u)
            cand[pos] = ((ull)bits << 32) | (unsigned)(~i);
    }
}

// ---------------------------------------------------------------- parallel sort: 4 local sorts + rank-merge
__global__ __launch_bounds__(1024) void sortA_kernel(const ull* __restrict__ cand,
                                                     const unsigned* __restrict__ meta,
                                                     ull* __restrict__ sorted) {
    __shared__ ull keys[2048];
    const int tid = threadIdx.x;
    const int base = blockIdx.x * 2048;
    const int n = min((int)meta[0], 8192);
    for (int i = tid; i < 2048; i += 1024) {
        int g = base + i;
        keys[i] = (g < n) ? cand[g] : (ull)(8191 - g);
    }
    __syncthreads();
    for (int k = 2; k <= 2048; k <<= 1) {
        for (int j = k >> 1; j >= 1; j >>= 1) {
            int s = tid;
            int i = ((s & ~(j - 1)) << 1) | (s & (j - 1));
            int p = i | j;
            ull a = keys[i], c = keys[p];
            bool desc = ((i & k) == 0);
            bool sw = desc ? (a < c) : (a > c);
            if (sw) { keys[i] = c; keys[p] = a; }
            __syncthreads();
        }
    }
    for (int i = tid; i < 2048; i += 1024) sorted[base + i] = keys[i];
}

__global__ __launch_bounds__(256) void merge_kernel(const ull* __restrict__ sorted,
                                                    ull* __restrict__ fin) {
    const int g = blockIdx.x * 256 + threadIdx.x;   // 32 blocks -> 8192
    ull x = sorted[g];
    const int c = g >> 11;
    int rank = g & 2047;
#pragma unroll
    for (int cc = 0; cc < 4; ++cc) {
        if (cc == c) continue;
        const ull* arr = sorted + cc * 2048;
        int lo = 0, hi = 2048;
        while (lo < hi) { int mid = (lo + hi) >> 1; if (arr[mid] > x) lo = mid + 1; else hi = mid; }
        rank += lo;
    }
    fin[rank] = x;
}

// ---------------------------------------------------------------- decode top-6000 (parallel)
__global__ __launch_bounds__(64) void decode_kernel(
    const ull* __restrict__ fin, const float* __restrict__ bb,
    float* __restrict__ selbox, float* __restrict__ selsc,
    ull* __restrict__ validbits)
{
    const int r = blockIdx.x * 64 + threadIdx.x;
    int valid = 0;
    if (r < PRENMS) {
        ull key = fin[r];
        unsigned sbits = (unsigned)(key >> 32);
        unsigned idx = ~(unsigned)(key & 0xFFFFFFFFull);
        float score = __uint_as_float(sbits);
        int p = (int)(idx / 9u);
        int a = (int)(idx - (unsigned)p * 9u);
        int y = p >> 7, x = p & 127;
        float d0 = bb[(a * 4 + 0) * NPIX + p];
        float d1 = bb[(a * 4 + 1) * NPIX + p];
        float d2 = bb[(a * 4 + 2) * NPIX + p];
        float d3 = bb[(a * 4 + 3) * NPIX + p];
        int ar_i = a / 3, sc_i = a - ar_i * 3;
        float arv = (ar_i == 0) ? 0.5f : ((ar_i == 1) ? 1.0f : 2.0f);
        float scv = (sc_i == 0) ? 128.f : ((sc_i == 1) ? 256.f : 512.f);
        float hr = sqrtf(arv);
        float wr = 1.0f / hr;
        float hs = hr * scv;
        float wsv = wr * scv;
        float bx1 = rintf(-wsv * 0.5f), by1 = rintf(-hs * 0.5f);
        float bx2 = rintf(wsv * 0.5f),  by2 = rintf(hs * 0.5f);
        float ax1 = x * 8.f + bx1, ay1 = y * 8.f + by1;
        float ax2 = x * 8.f + bx2, ay2 = y * 8.f + by2;
        float wa = ax2 - ax1, ha = ay2 - ay1;
        float cx = ax1 + 0.5f * wa, cy = ay1 + 0.5f * ha;
        float dw = fminf(d2, DW_CLIP_F), dh = fminf(d3, DW_CLIP_F);
        float px = d0 * wa + cx, py = d1 * ha + cy;
        float pw = expf(dw) * wa, ph = expf(dh) * ha;
        float x1 = px - 0.5f * pw, y1 = py - 0.5f * ph;
        float x2 = px + 0.5f * pw, y2 = py + 0.5f * ph;
        x1 = fminf(fmaxf(x1, 0.f), 1024.f);
        y1 = fminf(fmaxf(y1, 0.f), 1024.f);
        x2 = fminf(fmaxf(x2, 0.f), 1024.f);
        y2 = fminf(fmaxf(y2, 0.f), 1024.f);
        float bw = x2 - x1, bh = y2 - y1;
        valid = (bw >= 16.f) && (bh >= 16.f);
        selbox[r * 4 + 0] = x1; selbox[r * 4 + 1] = y1;
        selbox[r * 4 + 2] = x2; selbox[r * 4 + 3] = y2;
        selsc[r] = score;
    }
    ull bal = __ballot(valid);
    if (threadIdx.x == 0) validbits[blockIdx.x] = bal;
}

// ---------------------------------------------------------------- IOU suppression mask build
__global__ __launch_bounds__(256) void maskbuild_kernel(
    const float* __restrict__ selbox, ull* __restrict__ mask)
{
    __shared__ float jb0[64], jb1[64], jb2[64], jb3[64];
    const int jw = blockIdx.y;
    const int tid = threadIdx.x;
    const int i = blockIdx.x * 256 + tid;
    if (jw * 64 + 63 < blockIdx.x * 256) {
        if (i < PRENMS) mask[(size_t)i * MW + jw] = 0ull;
        return;
    }
    if (tid < 64) {
        int j = jw * 64 + tid;
        float x1 = 0.f, y1 = 0.f, x2 = 0.f, y2 = 0.f;
        if (j < PRENMS) {
            x1 = selbox[j * 4 + 0]; y1 = selbox[j * 4 + 1];
            x2 = selbox[j * 4 + 2]; y2 = selbox[j * 4 + 3];
        }
        jb0[tid] = x1; jb1[tid] = y1; jb2[tid] = x2; jb3[tid] = y2;
    }
    __syncthreads();
    if (i >= PRENMS) return;
    const float ix1 = selbox[i * 4 + 0], iy1 = selbox[i * 4 + 1];
    const float ix2 = selbox[i * 4 + 2], iy2 = selbox[i * 4 + 3];
    const float iarea = (ix2 - ix1) * (iy2 - iy1);
    ull word = 0ull;
    for (int b = 0; b < 64; ++b) {
        int j = jw * 64 + b;
        float xx1 = fmaxf(ix1, jb0[b]);
        float yy1 = fmaxf(iy1, jb1[b]);
        float xx2 = fminf(ix2, jb2[b]);
        float yy2 = fminf(iy2, jb3[b]);
        float iw = fmaxf(xx2 - xx1, 0.f);
        float ih = fmaxf(yy2 - yy1, 0.f);
        float inter = iw * ih;
        float jarea = (jb2[b] - jb0[b]) * (jb3[b] - jb1[b]);
        float iou = inter / (iarea + jarea - inter);
        if (j > i && iou > 0.7f) word |= (1ull << b);
    }
    mask[(size_t)i * MW + jw] = word;
}

// ---------------------------------------------------------------- chunked single-wave greedy NMS
__global__ __launch_bounds__(64) void nms_scan_kernel(
    const ull* __restrict__ validbits,
    const ull* __restrict__ mask,
    const float* __restrict__ selbox, const float* __restrict__ selsc,
    float* __restrict__ out)
{
    __shared__ int kept[POSTK];
    const int l = threadIdx.x;
    ull supp0 = ~validbits[l];
    ull supp1 = (l < 30) ? ~validbits[64 + l] : ~0ull;
    int nk = 0;
    ull ownrow_next = mask[(size_t)l * MW + 0];
    for (int wi = 0; wi < 94 && nk < POSTK; ++wi) {
        ull ownrow = ownrow_next;
        if (wi < 93) ownrow_next = mask[(size_t)((wi + 1) * 64 + l) * MW + (wi + 1)];
        ull wsup = (wi < 64) ? __shfl(supp0, wi) : __shfl(supp1, wi - 64);
        ull active = ~wsup;
        if (!active) continue;
        ull keptbits = 0ull;
        while (active && nk < POSTK) {
            int b = __builtin_ctzll(active);
            keptbits |= (1ull << b);
            if (l == 0) kept[nk] = wi * 64 + b;
            nk++;
            ull rowb = __shfl(ownrow, b);
            ull gt = (b == 63) ? 0ull : (~0ull << (b + 1));
            active &= gt & ~rowb;
        }
        while (keptbits) {
            int b0 = __builtin_ctzll(keptbits); keptbits &= keptbits - 1;
            int b1 = -1, b2 = -1, b3 = -1;
            if (keptbits) { b1 = __builtin_ctzll(keptbits); keptbits &= keptbits - 1; }
            if (keptbits) { b2 = __builtin_ctzll(keptbits); keptbits &= keptbits - 1; }
            if (keptbits) { b3 = __builtin_ctzll(keptbits); keptbits &= keptbits - 1; }
            const ull* r0 = mask + (size_t)(wi * 64 + b0) * MW;
            ull t0a = r0[l], t0b = (l < 30) ? r0[64 + l] : 0ull;
            ull t1a = 0, t1b = 0, t2a = 0, t2b = 0, t3a = 0, t3b = 0;
            if (b1 >= 0) { const ull* r1 = mask + (size_t)(wi * 64 + b1) * MW; t1a = r1[l]; t1b = (l < 30) ? r1[64 + l] : 0ull; }
            if (b2 >= 0) { const ull* r2 = mask + (size_t)(wi * 64 + b2) * MW; t2a = r2[l]; t2b = (l < 30) ? r2[64 + l] : 0ull; }
            if (b3 >= 0) { const ull* r3 = mask + (size_t)(wi * 64 + b3) * MW; t3a = r3[l]; t3b = (l < 30) ? r3[64 + l] : 0ull; }
            supp0 |= t0a | t1a | t2a | t3a;
            supp1 |= t0b | t1b | t2b | t3b;
        }
    }
    __syncthreads();
    for (int r = l; r < POSTK; r += 64) {
        if (r < nk) {
            int i = kept[r];
            out[r * 5 + 0] = selbox[i * 4 + 0];
            out[r * 5 + 1] = selbox[i * 4 + 1];
            out[r * 5 + 2] = selbox[i * 4 + 2];
            out[r * 5 + 3] = selbox[i * 4 + 3];
            out[r * 5 + 4] = selsc[i];
        } else {
            out[r * 5 + 0] = 0.f; out[r * 5 + 1] = 0.f;
            out[r * 5 + 2] = 0.f; out[r * 5 + 3] = 0.f;
            out[r * 5 + 4] = 0.f;
        }
    }
}

// ---------------------------------------------------------------- launch
extern "C" void kernel_launch(void* const* d_in, const int* in_sizes, int n_in,
                              void* d_out, int out_size, void* d_ws, size_t ws_size,
                              hipStream_t stream) {
    const float* feat    = (const float*)d_in[1];
    const float* conv_w  = (const float*)d_in[2];
    const float* conv_b  = (const float*)d_in[3];
    const float* cls_w   = (const float*)d_in[4];
    const float* cls_b   = (const float*)d_in[5];
    const float* bbox_w  = (const float*)d_in[6];
    const float* bbox_b  = (const float*)d_in[7];
    float* out = (float*)d_out;

    char* ws = (char*)d_ws;
    float*    part      = (float*)(ws + 0);                 // 33,554,432 (2 halves; half0 becomes rpn_feat)
    float*    rpn_feat  = part;                             // alias after combine
    float*    wt        = (float*)(ws + 33554432);          //  2,359,296
    float*    bb        = (float*)(ws + 35913728);          //  2,359,296
    float*    scores    = (float*)(ws + 38273024);          //    589,824
    unsigned* hist1     = (unsigned*)(ws + 38862848);       //     65,536
    unsigned* hist2     = (unsigned*)(ws + 38928384);       //    262,144
    unsigned* meta      = (unsigned*)(ws + 39190528);       //        256
    ull*      cand      = (ull*)(ws + 39190784);            //     65,536
    ull*      sorted    = (ull*)(ws + 39256320);            //     65,536
    ull*      fin       = (ull*)(ws + 39321856);            //     65,536
    float*    selbox    = (float*)(ws + 39387392);          //     96,256
    float*    selsc     = (float*)(ws + 39483648);          //     24,064
    ull*      validbits = (ull*)(ws + 39507712);            //        768
    ull*      mask      = (ull*)(ws + 39508480);            //  4,608,000  -> total 44,116,480

    {
        int nz = 16384 + 65536 + 64;  // hist1 + hist2 + meta contiguous
        zero_kernel<<<(nz + 255) / 256, 256, 0, stream>>>(hist1, nz);
    }
    wt_kernel<<<(2304 * 256 + 255) / 256, 256, 0, stream>>>(conv_w, wt);
    conv3x3_half_kernel<<<dim3(8, 8, 32), dim3(16, 16), 0, stream>>>(feat, wt, part);
    combine_kernel<<<4096, 256, 0, stream>>>(part, conv_b);
    heads_kernel<<<256, 64, 0, stream>>>(rpn_feat, cls_w, cls_b, bbox_w, bbox_b, scores, bb);
    hist1_kernel<<<64, 1024, 0, stream>>>(scores, hist1);
    scan1_kernel<<<1, 1024, 0, stream>>>(hist1, meta);
    hist2_kernel<<<(NSC + 255) / 256, 256, 0, stream>>>(scores, meta, hist2);
    scan2_kernel<<<1, 1024, 0, stream>>>(hist2, meta);
    compact_kernel<<<(NSC + 255) / 256, 256, 0, stream>>>(scores, meta, cand);
    sortA_kernel<<<4, 1024, 0, stream>>>(cand, meta, sorted);
    merge_kernel<<<32, 256, 0, stream>>>(sorted, fin);
    decode_kernel<<<94, 64, 0, stream>>>(fin, bb, selbox, selsc, validbits);
    maskbuild_kernel<<<dim3(24, 94), 256, 0, stream>>>(selbox, mask);
    nms_scan_kernel<<<1, 64, 0, stream>>>(validbits, mask, selbox, selsc, out);
}